// Round 10
// baseline (52.744 us; speedup 1.0000x reference)
//
#include <hip/hip_runtime.h>
#include <hip/hip_bf16.h>
#include <math.h>

#define HEADS 8
#define DH 32
#define DIM 256
#define INNER 256
#define B_ 2
#define S_ 8
#define H_ 32
#define W_ 16
#define NTOK (B_*S_*H_*W_)   /* 8192 */

// halo: 15 runs (3 ds x 5 hh) of 32 (hw = e&31, run = e>>5) = 480 entries.
// 5 waves per (row,head), 3 runs (96 entries) each: 6 QK tiles, 3 PV chunks.
// hw valid window: w2 = hw-2 in [0,16) and query window hw in [c, c+4].

// vT padded pitch: (VTOFF-2)%8==0 -> PV group bases 16B aligned.
#define VTPITCH (NTOK + 24)
#define VTOFF 10

typedef _Float16 h16;
typedef h16 half8 __attribute__((ext_vector_type(8)));
typedef float f32x4 __attribute__((ext_vector_type(4)));

#define QSCALE 0.17677669529663687f   /* 32^-0.5, folded into Q at proj */

// ---------------------------------------------------------------------------
// MFMA f16 GEMM (HW-validated R3/R4). OUT_MODE: 0=f32 row-major,
// 2=f16 transposed (vT), 3=f16 head-major ([col>>5][row][col&31]).
// oscale multiplies acc before bias/store (used to fold softmax scale into Q).
// ---------------------------------------------------------------------------
#define GBM 128
#define GBN 64
#define GBK 32
#define GPITCH 40

__device__ __forceinline__ uint4 cvt8(const float4 a, const float4 b) {
    union { h16 h[8]; uint4 u; } p;
    p.h[0] = (h16)a.x; p.h[1] = (h16)a.y; p.h[2] = (h16)a.z; p.h[3] = (h16)a.w;
    p.h[4] = (h16)b.x; p.h[5] = (h16)b.y; p.h[6] = (h16)b.z; p.h[7] = (h16)b.w;
    return p.u;
}

template <bool A_F16, int OUT_MODE>
__device__ __forceinline__ void mfma_gemm_tile_t(
    const void* __restrict__ Av, const float* __restrict__ W,
    const float* __restrict__ bias, void* __restrict__ outv,
    int m0, int j0, float oscale, h16* aT, h16* bT)
{
    const int tid  = threadIdx.x;
    const int lane = tid & 63;
    const int wid  = tid >> 6;
    const int wr   = wid >> 1;
    const int wc   = wid & 1;
    const int r    = lane & 15;
    const int g    = lane >> 4;

    f32x4 acc[4][2];
    #pragma unroll
    for (int i = 0; i < 4; ++i)
        #pragma unroll
        for (int j = 0; j < 2; ++j)
            acc[i][j] = (f32x4){0.f, 0.f, 0.f, 0.f};

    const int arow  = tid >> 1;
    const int ahalf = (tid & 1) * 16;
    const int brow  = (tid & 127) >> 1;
    const bool doB  = tid < 128;

    for (int k0 = 0; k0 < DIM; k0 += GBK) {
        if constexpr (A_F16) {
            const h16* A = (const h16*)Av;
            const h16* src = A + (size_t)(m0 + arow) * DIM + k0 + ahalf;
            *(uint4*)(aT + arow * GPITCH + ahalf + 0) = *(const uint4*)(src + 0);
            *(uint4*)(aT + arow * GPITCH + ahalf + 8) = *(const uint4*)(src + 8);
        } else {
            const float* A = (const float*)Av;
            const float* src = A + (size_t)(m0 + arow) * DIM + k0 + ahalf;
            const float4 u0 = *(const float4*)(src + 0);
            const float4 u1 = *(const float4*)(src + 4);
            const float4 u2 = *(const float4*)(src + 8);
            const float4 u3 = *(const float4*)(src + 12);
            *(uint4*)(aT + arow * GPITCH + ahalf + 0) = cvt8(u0, u1);
            *(uint4*)(aT + arow * GPITCH + ahalf + 8) = cvt8(u2, u3);
        }
        if (doB) {
            const float* src = W + (size_t)(j0 + brow) * DIM + k0 + ahalf;
            const float4 u0 = *(const float4*)(src + 0);
            const float4 u1 = *(const float4*)(src + 4);
            const float4 u2 = *(const float4*)(src + 8);
            const float4 u3 = *(const float4*)(src + 12);
            *(uint4*)(bT + brow * GPITCH + ahalf + 0) = cvt8(u0, u1);
            *(uint4*)(bT + brow * GPITCH + ahalf + 8) = cvt8(u2, u3);
        }
        __syncthreads();

        half8 af[4], bf[2];
        #pragma unroll
        for (int fr = 0; fr < 4; ++fr)
            af[fr] = *(const half8*)(aT + (wr * 64 + fr * 16 + r) * GPITCH + g * 8);
        #pragma unroll
        for (int fc = 0; fc < 2; ++fc)
            bf[fc] = *(const half8*)(bT + (wc * 32 + fc * 16 + r) * GPITCH + g * 8);

        #pragma unroll
        for (int fr = 0; fr < 4; ++fr)
            #pragma unroll
            for (int fc = 0; fc < 2; ++fc)
                acc[fr][fc] = __builtin_amdgcn_mfma_f32_16x16x32_f16(
                    af[fr], bf[fc], acc[fr][fc], 0, 0, 0);
        __syncthreads();
    }

    #pragma unroll
    for (int fr = 0; fr < 4; ++fr) {
        #pragma unroll
        for (int fc = 0; fc < 2; ++fc) {
            const int col = j0 + wc * 32 + fc * 16 + r;
            const float badd = bias ? bias[col] : 0.f;
            if constexpr (OUT_MODE == 2) {
                const int rowb = m0 + wr * 64 + fr * 16 + g * 4;
                union { h16 h[4]; uint u[2]; } p;
                #pragma unroll
                for (int i = 0; i < 4; ++i) p.h[i] = (h16)(acc[fr][fc][i] * oscale);
                h16* dst = (h16*)outv + (size_t)col * VTPITCH + VTOFF + rowb;
                *(uint*)(dst + 0) = p.u[0];
                *(uint*)(dst + 2) = p.u[1];
            } else if constexpr (OUT_MODE == 3) {
                const int hd = col >> 5, d = col & 31;
                #pragma unroll
                for (int i = 0; i < 4; ++i) {
                    const int row = m0 + wr * 64 + fr * 16 + g * 4 + i;
                    ((h16*)outv)[((size_t)hd * NTOK + row) * DH + d] =
                        (h16)(acc[fr][fc][i] * oscale);
                }
            } else {
                #pragma unroll
                for (int i = 0; i < 4; ++i) {
                    const int row = m0 + wr * 64 + fr * 16 + g * 4 + i;
                    ((float*)outv)[(size_t)row * INNER + col] =
                        acc[fr][fc][i] * oscale + badd;
                }
            }
        }
    }
}

// ---------------------------------------------------------------------------
// Kernel 1: projections. q (pre-scaled by QSCALE), k -> head-major f16
// [2][8][NTOK][32]; v -> vT f16 [INNER][VTPITCH] (data at +VTOFF).
// ---------------------------------------------------------------------------
__global__ __launch_bounds__(256) void proj_kernel(
    const float* __restrict__ x, const float* __restrict__ q,
    const float* __restrict__ wq, const float* __restrict__ wk,
    const float* __restrict__ wv, h16* __restrict__ qk, h16* __restrict__ vT)
{
    __shared__ h16 aT[GBM * GPITCH];
    __shared__ h16 bT[GBN * GPITCH];

    const int seg = blockIdx.y >> 2;
    const int jt  = blockIdx.y & 3;
    const float* A = (seg == 0) ? q : x;
    const float* W = (seg == 0) ? wq : ((seg == 1) ? wk : wv);

    if (seg == 2) {
        mfma_gemm_tile_t<false, 2>(A, W, nullptr, vT, blockIdx.x * GBM, jt * GBN,
                                   1.0f, aT, bT);
    } else {
        h16* outp = qk + (size_t)seg * HEADS * NTOK * DH;
        const float sc = (seg == 0) ? QSCALE : 1.0f;
        mfma_gemm_tile_t<false, 3>(A, W, nullptr, outp, blockIdx.x * GBM, jt * GBN,
                                   sc, aT, bT);
    }
}

// ---------------------------------------------------------------------------
// Kernel 2: MFMA local attention. grid = (512 rows, 8 heads), 320 thr = 5
// waves; wave wid handles runs [3*wid, 3*wid+3) (96 halo entries: 6 QK tiles,
// 3 PV chunks). Shift-based geometry (run=e>>5, hw=e&31), scalar run math via
// readfirstlane(wid) — no tables, no front barrier; all loads issue at start.
// 5-way flash merge via LDS. launch_bounds(320,4): VGPR cap 128 >= ~100 live
// (R7/R9 lesson: never cap below live state).
// ---------------------------------------------------------------------------
__global__ __launch_bounds__(320, 4) void attn_kernel(
    const h16* __restrict__ qk, const h16* __restrict__ vT, h16* __restrict__ ao)
{
    __shared__ float ms[5][2][16];      /* [wave][m,s][q] */
    __shared__ float obuf[4][64][9];    /* waves 1-4 partial O, padded */

    const int r_raw = blockIdx.x;
    const int r     = ((r_raw & 7) << 6) | (r_raw >> 3);   // XCD swizzle
    const int head  = blockIdx.y;
    const int tid   = threadIdx.x;
    const int lane  = tid & 63;
    const int wid   = __builtin_amdgcn_readfirstlane(tid >> 6);   // 0..4, SGPR

    const int h = r & 31, s = (r >> 5) & 7, b = r >> 8;
    const int n_base = r * 16;
    const int c = lane & 15, g = lane >> 4;

    // ---- scalar per-run precompute (runs 3*wid .. 3*wid+2) ----------------
    int   rowbase16[3];
    int   tbs[3];
    float kill[3];
    #pragma unroll
    for (int rr = 0; rr < 3; ++rr) {
        const int run = 3 * wid + rr;          // 0..14
        const int ds  = run / 5;
        const int hh  = run - ds * 5;
        const int s2  = s + ds - 1;
        const int h2  = h + hh - 2;
        const bool inb = ((unsigned)s2 < 8u) && ((unsigned)h2 < 32u);
        const int s2c = min(max(s2, 0), 7);
        const int h2c = min(max(h2, 0), 31);
        rowbase16[rr] = ((b * 8 + s2c) * 32 + h2c) * 16;
        tbs[rr]       = rowbase16[rr] + (VTOFF - 2);   // %8 == 0
        kill[rr]      = inb ? __builtin_inff() : -1e30f;
    }

    const h16* qb = qk + (size_t)head * NTOK * DH;
    const h16* kb = qk + (size_t)(HEADS + head) * NTOK * DH;

    // ---- issue ALL loads up front -----------------------------------------
    const half8 qf = *(const half8*)(qb + (size_t)(n_base + c) * DH + g * 8);

    half8 kf[6];
    #pragma unroll
    for (int t = 0; t < 6; ++t) {
        // tile t covers halo hw = 16*(t&1) + a (a = lane&15 = c supplies row a)
        const int w2c = (t & 1) ? min(c + 14, 15) : max(c - 2, 0);
        kf[t] = *(const half8*)(kb + (size_t)(rowbase16[t >> 1] + w2c) * DH + g * 8);
    }

    union u4h8 { uint4 u4; half8 hv; } vpre0[3], vpre1[3];
    const h16* vrow0 = vT + (size_t)(head * DH + c) * VTPITCH;
    const h16* vrow1 = vrow0 + (size_t)16 * VTPITCH;
    #pragma unroll
    for (int ch = 0; ch < 3; ++ch) {
        vpre0[ch].u4 = *(const uint4*)(vrow0 + tbs[ch] + 8 * g);
        vpre1[ch].u4 = *(const uint4*)(vrow1 + tbs[ch] + 8 * g);
    }

    // ---- QK (swapped): dots[t][i] = S[q=c][hw = 16(t&1)+4g+i, run=3wid+(t>>1)]
    f32x4 dots[6];
    #pragma unroll
    for (int t = 0; t < 6; ++t)
        dots[t] = __builtin_amdgcn_mfma_f32_16x16x32_f16(
            kf[t], qf, (f32x4){0.f, 0.f, 0.f, 0.f}, 0, 0, 0);

    // ---- mask + max (no LDS, no tables) -----------------------------------
    float mx = -1e30f;
    #pragma unroll
    for (int t = 0; t < 6; ++t) {
        const float kl = kill[t >> 1];
        #pragma unroll
        for (int i = 0; i < 4; ++i) {
            const int hw = (t & 1) * 16 + 4 * g + i;
            const bool okw = ((unsigned)(hw - c) <= 4u) &&
                             ((unsigned)(hw - 2) <= 15u);
            float dv = okw ? dots[t][i] : -1e30f;
            dv = fminf(dv, kl);               // kill whole out-of-bounds runs
            dots[t][i] = dv;
            mx = fmaxf(mx, dv);
        }
    }
    mx = fmaxf(mx, __shfl_xor(mx, 16));
    mx = fmaxf(mx, __shfl_xor(mx, 32));

    // ---- exp + sum + pack (dots pre-scaled; unnormalized P) ---------------
    float sum = 0.f;
    int d0[6], d1[6];
    #pragma unroll
    for (int t = 0; t < 6; ++t) {
        const float e0v = __expf(dots[t][0] - mx);
        const float e1v = __expf(dots[t][1] - mx);
        const float e2v = __expf(dots[t][2] - mx);
        const float e3v = __expf(dots[t][3] - mx);
        sum += (e0v + e1v) + (e2v + e3v);
        union { h16 hh2[2]; int u; } p0, p1;
        p0.hh2[0] = (h16)e0v; p0.hh2[1] = (h16)e1v;
        p1.hh2[0] = (h16)e2v; p1.hh2[1] = (h16)e3v;
        d0[t] = p0.u; d1[t] = p1.u;
    }
    sum += __shfl_xor(sum, 16);
    sum += __shfl_xor(sum, 32);

    if (lane < 16) {                    // per-q partial stats (q = lane)
        ms[wid][0][lane] = mx;
        ms[wid][1][lane] = sum;
    }

    // ---- PV: 3 chunks (= runs); A-frag via shfl, B-frag prefetched --------
    f32x4 o0 = (f32x4){0.f,0.f,0.f,0.f};
    f32x4 o1 = (f32x4){0.f,0.f,0.f,0.f};
    const bool hi = lane >= 32;
    const int l1 = ((lane & 16) ? 32 : 0) + c;
    const int l2 = l1 + 16;

    #pragma unroll
    for (int ch = 0; ch < 3; ++ch) {
        const int w0a = __shfl(d0[2*ch], l1), w0b = __shfl(d0[2*ch+1], l1);
        const int w1a = __shfl(d1[2*ch], l1), w1b = __shfl(d1[2*ch+1], l1);
        const int w2a = __shfl(d0[2*ch], l2), w2b = __shfl(d0[2*ch+1], l2);
        const int w3a = __shfl(d1[2*ch], l2), w3b = __shfl(d1[2*ch+1], l2);
        union { int u[4]; half8 hv; } pf;
        pf.u[0] = hi ? w0b : w0a;
        pf.u[1] = hi ? w1b : w1a;
        pf.u[2] = hi ? w2b : w2a;
        pf.u[3] = hi ? w3b : w3a;

        o0 = __builtin_amdgcn_mfma_f32_16x16x32_f16(pf.hv, vpre0[ch].hv, o0, 0, 0, 0);
        o1 = __builtin_amdgcn_mfma_f32_16x16x32_f16(pf.hv, vpre1[ch].hv, o1, 0, 0, 0);
    }

    // ---- publish waves 1-4, merge in wave 0, write ------------------------
    if (wid != 0) {
        #pragma unroll
        for (int i = 0; i < 4; ++i) {
            obuf[wid - 1][lane][i]     = o0[i];
            obuf[wid - 1][lane][4 + i] = o1[i];
        }
    }
    __syncthreads();

    if (wid == 0) {
        #pragma unroll
        for (int i = 0; i < 4; ++i) {
            const int qi = 4 * g + i;
            float m = ms[0][0][qi];
            #pragma unroll
            for (int qv = 1; qv < 5; ++qv) m = fmaxf(m, ms[qv][0][qi]);
            float ew[5], den = 0.f;
            #pragma unroll
            for (int qv = 0; qv < 5; ++qv) {
                ew[qv] = __expf(ms[qv][0][qi] - m);
                den += ms[qv][1][qi] * ew[qv];
            }
            den = 1.f / den;
            float r0 = o0[i] * ew[0];
            float r1 = o1[i] * ew[0];
            #pragma unroll
            for (int qv = 1; qv < 5; ++qv) {
                r0 += obuf[qv - 1][lane][i]     * ew[qv];
                r1 += obuf[qv - 1][lane][4 + i] * ew[qv];
            }
            const size_t row = (size_t)(n_base + qi) * INNER + head * DH;
            ao[row + c]      = (h16)(r0 * den);
            ao[row + 16 + c] = (h16)(r1 * den);
        }
    }
}

// ---------------------------------------------------------------------------
// Kernel 3: out = ao(f16) @ wo^T + bo   grid = (64, 4)
// ---------------------------------------------------------------------------
__global__ __launch_bounds__(256) void outproj_kernel(
    const h16* __restrict__ ao, const float* __restrict__ wo,
    const float* __restrict__ bo, float* __restrict__ out)
{
    __shared__ h16 aT[GBM * GPITCH];
    __shared__ h16 bT[GBN * GPITCH];
    mfma_gemm_tile_t<true, 0>(ao, wo, bo, out, blockIdx.x * GBM, blockIdx.y * GBN,
                              1.0f, aT, bT);
}

// ---------------------------------------------------------------------------
extern "C" void kernel_launch(void* const* d_in, const int* in_sizes, int n_in,
                              void* d_out, int out_size, void* d_ws, size_t ws_size,
                              hipStream_t stream) {
    const float* x  = (const float*)d_in[0];
    const float* q  = (const float*)d_in[1];
    const float* wq = (const float*)d_in[2];
    const float* wk = (const float*)d_in[3];
    const float* wv = (const float*)d_in[4];
    const float* wo = (const float*)d_in[5];
    const float* bo = (const float*)d_in[6];
    float* out = (float*)d_out;

    // ws: qk f16 [2][8][NTOK][32] (8MB) + vT f16 [INNER][VTPITCH] (4.2MB) + ao (4MB)
    h16* qk = (h16*)d_ws;
    h16* vT = qk + (size_t)2 * HEADS * NTOK * DH;
    h16* ao = vT + (size_t)INNER * VTPITCH;

    dim3 g1(NTOK / GBM, 12);
    proj_kernel<<<g1, 256, 0, stream>>>(x, q, wq, wk, wv, qk, vT);

    dim3 g2(NTOK / W_, HEADS);
    attn_kernel<<<g2, 320, 0, stream>>>(qk, vT, ao);

    dim3 g3(NTOK / GBM, INNER / GBN);
    outproj_kernel<<<g3, 256, 0, stream>>>(ao, wo, bo, out);
}

// Round 11
// 46.079 us; speedup vs baseline: 1.1446x; 1.1446x over previous
//
#include <hip/hip_runtime.h>
#include <hip/hip_bf16.h>
#include <math.h>

#define HEADS 8
#define DH 32
#define DIM 256
#define INNER 256
#define B_ 2
#define S_ 8
#define H_ 32
#define W_ 16
#define NTOK (B_*S_*H_*W_)   /* 8192 */

// vT: [d][VTPITCH], data at +VTOFF. VTOFF=8 -> 16-token row starts 16B-aligned.
#define VTPITCH (NTOK + 16)
#define VTOFF 8

// attn LDS geometry: block halo = 3 ds x 8 lh rows of 16 tokens (24 krows).
#define KPITCH 40            /* h16 per K token (32 + 8 pad) */
#define VPITCH 392           /* h16 per Vlds d-row (24*16 = 384 + 8 pad) */

typedef _Float16 h16;
typedef h16 half8 __attribute__((ext_vector_type(8)));
typedef float f32x4 __attribute__((ext_vector_type(4)));

#define QSCALE 0.17677669529663687f   /* 32^-0.5, folded into Q at proj */

// ---------------------------------------------------------------------------
// MFMA f16 GEMM (HW-validated R3+). OUT_MODE: 0=f32 row-major,
// 2=f16 transposed (vT), 3=f16 head-major ([col>>5][row][col&31]).
// ---------------------------------------------------------------------------
#define GBM 128
#define GBN 64
#define GBK 32
#define GPITCH 40

__device__ __forceinline__ uint4 cvt8(const float4 a, const float4 b) {
    union { h16 h[8]; uint4 u; } p;
    p.h[0] = (h16)a.x; p.h[1] = (h16)a.y; p.h[2] = (h16)a.z; p.h[3] = (h16)a.w;
    p.h[4] = (h16)b.x; p.h[5] = (h16)b.y; p.h[6] = (h16)b.z; p.h[7] = (h16)b.w;
    return p.u;
}

template <bool A_F16, int OUT_MODE>
__device__ __forceinline__ void mfma_gemm_tile_t(
    const void* __restrict__ Av, const float* __restrict__ W,
    const float* __restrict__ bias, void* __restrict__ outv,
    int m0, int j0, float oscale, h16* aT, h16* bT)
{
    const int tid  = threadIdx.x;
    const int lane = tid & 63;
    const int wid  = tid >> 6;
    const int wr   = wid >> 1;
    const int wc   = wid & 1;
    const int r    = lane & 15;
    const int g    = lane >> 4;

    f32x4 acc[4][2];
    #pragma unroll
    for (int i = 0; i < 4; ++i)
        #pragma unroll
        for (int j = 0; j < 2; ++j)
            acc[i][j] = (f32x4){0.f, 0.f, 0.f, 0.f};

    const int arow  = tid >> 1;
    const int ahalf = (tid & 1) * 16;
    const int brow  = (tid & 127) >> 1;
    const bool doB  = tid < 128;

    for (int k0 = 0; k0 < DIM; k0 += GBK) {
        if constexpr (A_F16) {
            const h16* A = (const h16*)Av;
            const h16* src = A + (size_t)(m0 + arow) * DIM + k0 + ahalf;
            *(uint4*)(aT + arow * GPITCH + ahalf + 0) = *(const uint4*)(src + 0);
            *(uint4*)(aT + arow * GPITCH + ahalf + 8) = *(const uint4*)(src + 8);
        } else {
            const float* A = (const float*)Av;
            const float* src = A + (size_t)(m0 + arow) * DIM + k0 + ahalf;
            const float4 u0 = *(const float4*)(src + 0);
            const float4 u1 = *(const float4*)(src + 4);
            const float4 u2 = *(const float4*)(src + 8);
            const float4 u3 = *(const float4*)(src + 12);
            *(uint4*)(aT + arow * GPITCH + ahalf + 0) = cvt8(u0, u1);
            *(uint4*)(aT + arow * GPITCH + ahalf + 8) = cvt8(u2, u3);
        }
        if (doB) {
            const float* src = W + (size_t)(j0 + brow) * DIM + k0 + ahalf;
            const float4 u0 = *(const float4*)(src + 0);
            const float4 u1 = *(const float4*)(src + 4);
            const float4 u2 = *(const float4*)(src + 8);
            const float4 u3 = *(const float4*)(src + 12);
            *(uint4*)(bT + brow * GPITCH + ahalf + 0) = cvt8(u0, u1);
            *(uint4*)(bT + brow * GPITCH + ahalf + 8) = cvt8(u2, u3);
        }
        __syncthreads();

        half8 af[4], bf[2];
        #pragma unroll
        for (int fr = 0; fr < 4; ++fr)
            af[fr] = *(const half8*)(aT + (wr * 64 + fr * 16 + r) * GPITCH + g * 8);
        #pragma unroll
        for (int fc = 0; fc < 2; ++fc)
            bf[fc] = *(const half8*)(bT + (wc * 32 + fc * 16 + r) * GPITCH + g * 8);

        #pragma unroll
        for (int fr = 0; fr < 4; ++fr)
            #pragma unroll
            for (int fc = 0; fc < 2; ++fc)
                acc[fr][fc] = __builtin_amdgcn_mfma_f32_16x16x32_f16(
                    af[fr], bf[fc], acc[fr][fc], 0, 0, 0);
        __syncthreads();
    }

    #pragma unroll
    for (int fr = 0; fr < 4; ++fr) {
        #pragma unroll
        for (int fc = 0; fc < 2; ++fc) {
            const int col = j0 + wc * 32 + fc * 16 + r;
            const float badd = bias ? bias[col] : 0.f;
            if constexpr (OUT_MODE == 2) {
                // f16 transposed: out[col][VTOFF + row]; (VTOFF+4k)*2 bytes is
                // 8B-aligned -> single uint2 store.
                const int rowb = m0 + wr * 64 + fr * 16 + g * 4;
                union { h16 h[4]; uint2 u; } p;
                #pragma unroll
                for (int i = 0; i < 4; ++i) p.h[i] = (h16)(acc[fr][fc][i] * oscale);
                *(uint2*)((h16*)outv + (size_t)col * VTPITCH + VTOFF + rowb) = p.u;
            } else if constexpr (OUT_MODE == 3) {
                const int hd = col >> 5, d = col & 31;
                #pragma unroll
                for (int i = 0; i < 4; ++i) {
                    const int row = m0 + wr * 64 + fr * 16 + g * 4 + i;
                    ((h16*)outv)[((size_t)hd * NTOK + row) * DH + d] =
                        (h16)(acc[fr][fc][i] * oscale);
                }
            } else {
                #pragma unroll
                for (int i = 0; i < 4; ++i) {
                    const int row = m0 + wr * 64 + fr * 16 + g * 4 + i;
                    ((float*)outv)[(size_t)row * INNER + col] =
                        acc[fr][fc][i] * oscale + badd;
                }
            }
        }
    }
}

// ---------------------------------------------------------------------------
// Kernel 1: projections. q (pre-scaled), k -> head-major f16 [2][8][NTOK][32];
// v -> vT f16 [INNER][VTPITCH] (data at +VTOFF).
// ---------------------------------------------------------------------------
__global__ __launch_bounds__(256) void proj_kernel(
    const float* __restrict__ x, const float* __restrict__ q,
    const float* __restrict__ wq, const float* __restrict__ wk,
    const float* __restrict__ wv, h16* __restrict__ qk, h16* __restrict__ vT)
{
    __shared__ h16 aT[GBM * GPITCH];
    __shared__ h16 bT[GBN * GPITCH];

    const int seg = blockIdx.y >> 2;
    const int jt  = blockIdx.y & 3;
    const float* A = (seg == 0) ? q : x;
    const float* W = (seg == 0) ? wq : ((seg == 1) ? wk : wv);

    if (seg == 2) {
        mfma_gemm_tile_t<false, 2>(A, W, nullptr, vT, blockIdx.x * GBM, jt * GBN,
                                   1.0f, aT, bT);
    } else {
        h16* outp = qk + (size_t)seg * HEADS * NTOK * DH;
        const float sc = (seg == 0) ? QSCALE : 1.0f;
        mfma_gemm_tile_t<false, 3>(A, W, nullptr, outp, blockIdx.x * GBM, jt * GBN,
                                   sc, aT, bT);
    }
}

// ---------------------------------------------------------------------------
// Kernel 2: LDS-staged MFMA local attention (no global gathers).
// grid = (128 tiles, 8 heads), 512 thr = 8 waves.
// Tile = (b, s, 4 h-rows). Stage K halo (24 krows = 3 ds x 8 lh, 16 tok x 64B
// each, coalesced) + V^T (32 d-rows x 384 cols from vT) into LDS once.
// Wave w = (q-row qr = w>>1, half = w&1): 8 runs of 16 (run 15 fictitious,
// masked); 8 QK MFMA + in-register softmax + 4 PV chunks, all frags from LDS.
// 2-way flash merge per q-row via ms + obuf (obuf aliases Klds after barrier).
// ---------------------------------------------------------------------------
__global__ __launch_bounds__(512, 4) void attn_kernel(
    const h16* __restrict__ qk, const h16* __restrict__ vT, h16* __restrict__ ao)
{
    __shared__ __align__(16) h16 Klds[24][16][KPITCH];   /* 30720 B */
    __shared__ __align__(16) h16 Vlds[32][VPITCH];       /* 25088 B */
    __shared__ float ms[8][2][16];                       /* [wave][m,s][q] */

    const int xr   = blockIdx.x;
    const int tile = ((xr & 7) << 4) | (xr >> 3);        // XCD swizzle (128=8*16)
    const int head = blockIdx.y;
    const int tid  = threadIdx.x;
    const int lane = tid & 63;
    const int wid  = __builtin_amdgcn_readfirstlane(tid >> 6);   // 0..7
    const int qr   = wid >> 1;
    const int half = wid & 1;

    const int b = tile >> 6, s = (tile >> 3) & 7, h4b = (tile & 7) * 4;
    const int c = lane & 15, g = lane >> 4;

    const h16* qb = qk + (size_t)head * NTOK * DH;
    const h16* kb = qk + (size_t)(HEADS + head) * NTOK * DH;

    // ---- stage K: wave wid stages krows 3*wid .. 3*wid+2 (1KB each) -------
    #pragma unroll
    for (int kk = 0; kk < 3; ++kk) {
        const int krow = 3 * wid + kk;                 // 0..23
        const int ds = krow >> 3, lh = krow & 7;
        const int s2c = min(max(s + ds - 1, 0), 7);
        const int h2c = min(max(h4b + lh - 2, 0), 31);
        const int tokbase = ((b * 8 + s2c) * 32 + h2c) * 16;
        const int tok = lane >> 2, sl = lane & 3;
        const uint4 v = *(const uint4*)(kb + (size_t)(tokbase + tok) * DH + sl * 8);
        *(uint4*)&Klds[krow][tok][sl * 8] = v;
    }
    // ---- stage V^T: 768 chunks (d, krow) of 32B over 512 threads ----------
    #pragma unroll
    for (int pass = 0; pass < 2; ++pass) {
        const int chn = tid + pass * 512;
        if (chn < 768) {
            const int d = chn & 31, krow = chn >> 5;
            const int ds = krow >> 3, lh = krow & 7;
            const int s2c = min(max(s + ds - 1, 0), 7);
            const int h2c = min(max(h4b + lh - 2, 0), 31);
            const int tokbase = ((b * 8 + s2c) * 32 + h2c) * 16;
            const h16* src = vT + (size_t)(head * DH + d) * VTPITCH + VTOFF + tokbase;
            const uint4 v0 = *(const uint4*)(src + 0);
            const uint4 v1 = *(const uint4*)(src + 8);
            *(uint4*)&Vlds[d][krow * 16 + 0] = v0;
            *(uint4*)&Vlds[d][krow * 16 + 8] = v1;
        }
    }
    __syncthreads();

    // ---- per-run scalars (SALU): runs half*8 .. half*8+7 ------------------
    int   kr[8];
    float kill[8];
    #pragma unroll
    for (int rr = 0; rr < 8; ++rr) {
        const int run = half * 8 + rr;                 // 0..15 (15 fictitious)
        if (run < 15) {
            const int ds = run / 5, hh = run - 5 * ds;
            const int s2 = s + ds - 1;
            const int h2 = h4b + qr + hh - 2;
            const bool inb = ((unsigned)s2 < 8u) && ((unsigned)h2 < 32u);
            kr[rr]   = ds * 8 + qr + hh;               // 0..23
            kill[rr] = inb ? __builtin_inff() : -1e30f;
        } else {
            kr[rr]   = 0;
            kill[rr] = -1e30f;
        }
    }

    // ---- Q fragment -------------------------------------------------------
    const int n_row = ((b * 8 + s) * 32 + h4b + qr) * 16;
    const half8 qf = *(const half8*)(qb + (size_t)(n_row + c) * DH + g * 8);

    // ---- QK (swapped): dots[rr][i] = S[w2 = 4g+i][q = c] for run rr -------
    f32x4 dots[8];
    #pragma unroll
    for (int rr = 0; rr < 8; ++rr) {
        const half8 kf = *(const half8*)&Klds[kr[rr]][c][g * 8];
        dots[rr] = __builtin_amdgcn_mfma_f32_16x16x32_f16(
            kf, qf, (f32x4){0.f, 0.f, 0.f, 0.f}, 0, 0, 0);
    }

    // ---- mask + max -------------------------------------------------------
    float mx = -1e30f;
    #pragma unroll
    for (int rr = 0; rr < 8; ++rr) {
        const float kl = kill[rr];
        #pragma unroll
        for (int i = 0; i < 4; ++i) {
            const int w2 = 4 * g + i;
            const bool okw = ((unsigned)(w2 - c + 2) <= 4u);   // |w2-c| <= 2
            float dv = okw ? dots[rr][i] : -1e30f;
            dv = fminf(dv, kl);
            dots[rr][i] = dv;
            mx = fmaxf(mx, dv);
        }
    }
    mx = fmaxf(mx, __shfl_xor(mx, 16));
    mx = fmaxf(mx, __shfl_xor(mx, 32));

    // ---- exp + sum + pack (unnormalized P, f16) ---------------------------
    float sum = 0.f;
    int d0[8], d1[8];
    #pragma unroll
    for (int rr = 0; rr < 8; ++rr) {
        const float e0v = __expf(dots[rr][0] - mx);
        const float e1v = __expf(dots[rr][1] - mx);
        const float e2v = __expf(dots[rr][2] - mx);
        const float e3v = __expf(dots[rr][3] - mx);
        sum += (e0v + e1v) + (e2v + e3v);
        union { h16 hh2[2]; int u; } p0, p1;
        p0.hh2[0] = (h16)e0v; p0.hh2[1] = (h16)e1v;
        p1.hh2[0] = (h16)e2v; p1.hh2[1] = (h16)e3v;
        d0[rr] = p0.u; d1[rr] = p1.u;
    }
    sum += __shfl_xor(sum, 16);
    sum += __shfl_xor(sum, 32);

    if (lane < 16) {                     // per-q stats (q = lane)
        ms[wid][0][lane] = mx;
        ms[wid][1][lane] = sum;
    }

    // ---- PV: 4 chunks of 32 (run pairs); A-frag via shfl, B-frag from LDS -
    f32x4 o0 = (f32x4){0.f,0.f,0.f,0.f};
    f32x4 o1 = (f32x4){0.f,0.f,0.f,0.f};
    const bool hi = lane >= 32;
    const int l1 = ((lane & 16) ? 32 : 0) + c;
    const int l2 = l1 + 16;

    #pragma unroll
    for (int ch = 0; ch < 4; ++ch) {
        const int w0a = __shfl(d0[2*ch], l1), w0b = __shfl(d0[2*ch+1], l1);
        const int w1a = __shfl(d1[2*ch], l1), w1b = __shfl(d1[2*ch+1], l1);
        const int w2a = __shfl(d0[2*ch], l2), w2b = __shfl(d0[2*ch+1], l2);
        const int w3a = __shfl(d1[2*ch], l2), w3b = __shfl(d1[2*ch+1], l2);
        union { int u[4]; half8 hv; } pf;
        pf.u[0] = hi ? w0b : w0a;
        pf.u[1] = hi ? w1b : w1a;
        pf.u[2] = hi ? w2b : w2a;
        pf.u[3] = hi ? w3b : w3a;

        // B-frag: lane (c,g) needs V^T[d = c / c+16][chunk entries 8g..8g+7];
        // entries k<16 live in run 2ch (krow kr[2ch]), k>=16 in run 2ch+1.
        const int col = (g < 2) ? (kr[2*ch] * 16 + 8 * g)
                                : (kr[2*ch+1] * 16 + 8 * g - 16);
        const half8 v0 = *(const half8*)&Vlds[c][col];
        const half8 v1 = *(const half8*)&Vlds[c + 16][col];

        o0 = __builtin_amdgcn_mfma_f32_16x16x32_f16(pf.hv, v0, o0, 0, 0, 0);
        o1 = __builtin_amdgcn_mfma_f32_16x16x32_f16(pf.hv, v1, o1, 0, 0, 0);
    }

    // ---- merge halves (obuf aliases Klds; safe after barrier) -------------
    __syncthreads();                     // all LDS K/V reads done
    float* obuf = (float*)&Klds[0][0][0];   // [4][64][9] floats = 9216 B

    if (half == 1) {
        #pragma unroll
        for (int i = 0; i < 4; ++i) {
            obuf[(qr * 64 + lane) * 9 + i]     = o0[i];
            obuf[(qr * 64 + lane) * 9 + 4 + i] = o1[i];
        }
    }
    __syncthreads();

    if (half == 0) {
        #pragma unroll
        for (int i = 0; i < 4; ++i) {
            const int qi = 4 * g + i;
            const float m_a = ms[wid][0][qi],     s_a = ms[wid][1][qi];
            const float m_b = ms[wid | 1][0][qi], s_b = ms[wid | 1][1][qi];
            const float m  = fmaxf(m_a, m_b);
            const float ea = __expf(m_a - m);
            const float eb = __expf(m_b - m);
            const float den = 1.f / (s_a * ea + s_b * eb);
            const float ob0 = obuf[(qr * 64 + lane) * 9 + i];
            const float ob1 = obuf[(qr * 64 + lane) * 9 + 4 + i];
            const float r0 = (o0[i] * ea + ob0 * eb) * den;
            const float r1 = (o1[i] * ea + ob1 * eb) * den;
            const size_t row = (size_t)(n_row + qi) * INNER + head * DH;
            ao[row + c]      = (h16)r0;
            ao[row + 16 + c] = (h16)r1;
        }
    }
}

// ---------------------------------------------------------------------------
// Kernel 3: out = ao(f16) @ wo^T + bo   grid = (64, 4)
// ---------------------------------------------------------------------------
__global__ __launch_bounds__(256) void outproj_kernel(
    const h16* __restrict__ ao, const float* __restrict__ wo,
    const float* __restrict__ bo, float* __restrict__ out)
{
    __shared__ h16 aT[GBM * GPITCH];
    __shared__ h16 bT[GBN * GPITCH];
    mfma_gemm_tile_t<true, 0>(ao, wo, bo, out, blockIdx.x * GBM, blockIdx.y * GBN,
                              1.0f, aT, bT);
}

// ---------------------------------------------------------------------------
extern "C" void kernel_launch(void* const* d_in, const int* in_sizes, int n_in,
                              void* d_out, int out_size, void* d_ws, size_t ws_size,
                              hipStream_t stream) {
    const float* x  = (const float*)d_in[0];
    const float* q  = (const float*)d_in[1];
    const float* wq = (const float*)d_in[2];
    const float* wk = (const float*)d_in[3];
    const float* wv = (const float*)d_in[4];
    const float* wo = (const float*)d_in[5];
    const float* bo = (const float*)d_in[6];
    float* out = (float*)d_out;

    // ws: qk f16 [2][8][NTOK][32] (8MB) + vT f16 [INNER][VTPITCH] (4.2MB) + ao (4MB)
    h16* qk = (h16*)d_ws;
    h16* vT = qk + (size_t)2 * HEADS * NTOK * DH;
    h16* ao = vT + (size_t)INNER * VTPITCH;

    dim3 g1(NTOK / GBM, 12);
    proj_kernel<<<g1, 256, 0, stream>>>(x, q, wq, wk, wv, qk, vT);

    dim3 g2(128, HEADS);
    attn_kernel<<<g2, 512, 0, stream>>>(qk, vT, ao);

    dim3 g3(NTOK / GBM, INNER / GBN);
    outproj_kernel<<<g3, 256, 0, stream>>>(ao, wo, bo, out);
}